// Round 6
// baseline (456.378 us; speedup 1.0000x reference)
//
#include <hip/hip_runtime.h>
#include <hip/hip_bf16.h>

#define N1 8192
#define N2 8192
#define CDIM 128
#define HC 60
#define WC 80
#define HIMG 480
#define WIMG 640
#define INV_DENOM (1.0f / (8192.0f * 256.0f))

using bf16x8 = __attribute__((ext_vector_type(8))) short;
using f32x4  = __attribute__((ext_vector_type(4))) float;

__device__ __forceinline__ ushort f2bf(float f) {
    union { float f; unsigned u; } x; x.f = f;
    unsigned u = x.u;
    unsigned r = (u + 0x7FFFu + ((u >> 16) & 1u)) >> 16;
    return (ushort)r;
}
__device__ __forceinline__ float bf2f(unsigned bits) {
    union { unsigned u; float f; } x; x.u = bits << 16; return x.f;
}

// ---------- fp32 -> bf16 convert (vectorized) ----------
__global__ void cvt_kernel(const float* __restrict__ in, ushort* __restrict__ out, int n4) {
    int i = blockIdx.x * blockDim.x + threadIdx.x;
    if (i < n4) {
        float4 v = ((const float4*)in)[i];
        ushort4 o;
        o.x = f2bf(v.x); o.y = f2bf(v.y); o.z = f2bf(v.z); o.w = f2bf(v.w);
        ((ushort4*)out)[i] = o;
    }
}

// ---------- positive term ----------
__global__ void pos_kernel(const float* __restrict__ wkp1,
                           const float* __restrict__ kp1d,
                           const float* __restrict__ desc2,
                           float* __restrict__ out) {
    const int i = blockIdx.x;
    const int c = threadIdx.x;            // 128 threads = 2 waves
    float y = wkp1[2 * i], x = wkp1[2 * i + 1];
    float py = fminf(fmaxf(y / (float)(HIMG - 1) * (float)(HC - 1), 0.0f), (float)(HC - 1));
    float px = fminf(fmaxf(x / (float)(WIMG - 1) * (float)(WC - 1), 0.0f), (float)(WC - 1));
    int y0 = min(max((int)floorf(py), 0), HC - 2);
    int x0 = min(max((int)floorf(px), 0), WC - 2);
    float wy = py - (float)y0;
    float wx = px - (float)x0;
    const float* d = desc2 + (size_t)c * (HC * WC) + y0 * WC + x0;
    float v00 = d[0], v01 = d[1], v10 = d[WC], v11 = d[WC + 1];
    float v = v00 * (1.0f - wy) * (1.0f - wx) + v01 * (1.0f - wy) * wx
            + v10 * wy * (1.0f - wx) + v11 * wy * wx;
    float a = kp1d[(size_t)i * CDIM + c];
    float s2 = v * v, sav = a * v;
    #pragma unroll
    for (int off = 32; off >= 1; off >>= 1) {
        s2  += __shfl_down(s2, off);
        sav += __shfl_down(sav, off);
    }
    __shared__ float p2[2], pav[2];
    int wave = threadIdx.x >> 6, lane = threadIdx.x & 63;
    if (lane == 0) { p2[wave] = s2; pav[wave] = sav; }
    __syncthreads();
    if (threadIdx.x == 0) {
        float nrm = sqrtf(p2[0] + p2[1]);
        float pd = (pav[0] + pav[1]) / fmaxf(nrm, 1e-12f);
        float l = fmaxf(1.0f - pd, 0.0f) * (256.0f / 3.0f);
        atomicAdd(out, l * INV_DENOM);
    }
}

// ---------- masked GEMM -> bf16 dots ----------
__global__ __launch_bounds__(256, 2)
void gemm_kernel(const ushort* __restrict__ A, const ushort* __restrict__ B,
                 const float* __restrict__ wkp1, const float* __restrict__ kp2,
                 ushort* __restrict__ dots, int m_off) {
    const int n0 = blockIdx.x * 128;
    const int m0 = m_off + blockIdx.y * 128;
    const int lane = threadIdx.x & 63;
    const int wave = threadIdx.x >> 6;
    const int wm = wave >> 1, wn = wave & 1;
    const int lrow = lane & 15, quad = lane >> 4;

    f32x4 acc[4][4];
    #pragma unroll
    for (int i = 0; i < 4; i++)
        #pragma unroll
        for (int j = 0; j < 4; j++) acc[i][j] = (f32x4){0.f, 0.f, 0.f, 0.f};

    const int mbase = m0 + wm * 64 + lrow;
    const int nbase = n0 + wn * 64 + lrow;
    #pragma unroll
    for (int kit = 0; kit < 4; kit++) {
        const int kk = kit * 32 + quad * 8;
        bf16x8 af[4], bfr[4];
        #pragma unroll
        for (int t = 0; t < 4; t++) {
            af[t]  = *(const bf16x8*)(A + (size_t)(mbase + t * 16) * CDIM + kk);
            bfr[t] = *(const bf16x8*)(B + (size_t)(nbase + t * 16) * CDIM + kk);
        }
        #pragma unroll
        for (int mt = 0; mt < 4; mt++)
            #pragma unroll
            for (int nt = 0; nt < 4; nt++)
                acc[mt][nt] = __builtin_amdgcn_mfma_f32_16x16x32_bf16(
                    af[mt], bfr[nt], acc[mt][nt], 0, 0, 0);
    }

    const float thr = 2.0f * sqrtf(32.0f) + 0.1f;
    const float thr2 = thr * thr;
    #pragma unroll
    for (int nt = 0; nt < 4; nt++) {
        int j = n0 + wn * 64 + nt * 16 + lrow;       // C/D: col = lane&15
        float ky = kp2[2 * j], kx = kp2[2 * j + 1];
        #pragma unroll
        for (int mt = 0; mt < 4; mt++) {
            #pragma unroll
            for (int r = 0; r < 4; r++) {
                int i = m0 + wm * 64 + mt * 16 + quad * 4 + r;  // row = (lane>>4)*4 + reg
                float wy = wkp1[2 * i], wx = wkp1[2 * i + 1];
                float dy = wy - ky, dx = wx - kx;
                float v = acc[mt][nt][r];
                if (dy * dy + dx * dx <= thr2) v -= 5.0f;
                dots[(size_t)(i - m_off) * N2 + j] = f2bf(v);
            }
        }
    }
}

// ---------- per-row top-256 hinge sum (two-level BYTE histogram, exact) ----------
// bf16 monotone key = bits ^ (sign?0xFFFF:0x8000). Level 1: 256 bins on the
// key HIGH byte (pure shifts, no float binning). Level 2: within the boundary
// high-bin, 256 bins on the key LOW byte -- a (high,low) cell pins the value
// EXACTLY, so rank/tie handling is closed-form: no list, no bisection, no
// per-element counter atomics, no wave0-only tail loops. LDS ~6.3 KB ->
// 8 blocks/CU residency (vs ~4 at R5's 21 KB).
__global__ __launch_bounds__(256)
void select_kernel(const ushort* __restrict__ dots, float* __restrict__ out) {
    const int row = blockIdx.x;
    const int t = threadIdx.x;
    const int lane = t & 63, wave = t >> 6;

    __shared__ unsigned hist[4][256];
    __shared__ unsigned lowcnt[256];
    __shared__ float    lowsum[256];
    __shared__ int   s_b, s_r;
    __shared__ float s_s[4];

    #pragma unroll
    for (int i = 0; i < 4; i++) hist[i][t] = 0u;
    lowcnt[t] = 0u; lowsum[t] = 0.f;
    if (t < 4) s_s[t] = 0.f;
    __syncthreads();

    const uint4* rp4 = (const uint4*)(dots + (size_t)row * N2);  // 8 bf16 per uint4
    uint4 w0 = rp4[t], w1 = rp4[256 + t], w2 = rp4[512 + t], w3 = rp4[768 + t];

    // ---- pass 1: high-byte histogram (wave-privatized)
    {
        unsigned wd[16] = {w0.x, w0.y, w0.z, w0.w, w1.x, w1.y, w1.z, w1.w,
                           w2.x, w2.y, w2.z, w2.w, w3.x, w3.y, w3.z, w3.w};
        #pragma unroll
        for (int u = 0; u < 16; u++) {
            unsigned x = wd[u];
            unsigned kk = x ^ 0x80008000u ^ (((x >> 15) & 0x00010001u) * 0x7FFFu);
            atomicAdd(&hist[wave][(kk >> 8) & 0xFFu], 1u);
            atomicAdd(&hist[wave][kk >> 24], 1u);
        }
    }
    __syncthreads();

    // ---- wave 0: suffix scan over 256 high bins (4 bins/lane) -> b, r
    if (wave == 0) {
        int c0 = hist[0][4*lane+0] + hist[1][4*lane+0] + hist[2][4*lane+0] + hist[3][4*lane+0];
        int c1 = hist[0][4*lane+1] + hist[1][4*lane+1] + hist[2][4*lane+1] + hist[3][4*lane+1];
        int c2 = hist[0][4*lane+2] + hist[1][4*lane+2] + hist[2][4*lane+2] + hist[3][4*lane+2];
        int c3 = hist[0][4*lane+3] + hist[1][4*lane+3] + hist[2][4*lane+3] + hist[3][4*lane+3];
        int suf3 = c3, suf2 = c2 + suf3, suf1 = c1 + suf2, suf0 = c0 + suf1;
        int inc = suf0;
        #pragma unroll
        for (int off = 1; off < 64; off <<= 1) {
            int tmp = __shfl_down(inc, off);
            inc += (lane + off < 64) ? tmp : 0;
        }
        int eAbove = inc - suf0;
        int S0 = suf0 + eAbove, S1 = suf1 + eAbove, S2 = suf2 + eAbove, S3 = suf3 + eAbove;
        int SN0 = S1, SN1 = S2, SN2 = S3, SN3 = eAbove;
        if (S0 >= 256 && SN0 < 256) { s_b = 4*lane+0; s_r = 256 - SN0; }
        if (S1 >= 256 && SN1 < 256) { s_b = 4*lane+1; s_r = 256 - SN1; }
        if (S2 >= 256 && SN2 < 256) { s_b = 4*lane+2; s_r = 256 - SN2; }
        if (S3 >= 256 && SN3 < 256) { s_b = 4*lane+3; s_r = 256 - SN3; }
    }
    __syncthreads();
    const int bb = s_b;
    const int r  = s_r;      // rank within high-bin bb, 1 <= r <= cnt[bb]

    // ---- pass 2: high>bb -> accumulate; high==bb -> low-byte cnt+sum
    float sloc = 0.f;
    {
        unsigned wd[16] = {w0.x, w0.y, w0.z, w0.w, w1.x, w1.y, w1.z, w1.w,
                           w2.x, w2.y, w2.z, w2.w, w3.x, w3.y, w3.z, w3.w};
        #pragma unroll
        for (int u = 0; u < 16; u++) {
            unsigned x = wd[u];
            unsigned kk = x ^ 0x80008000u ^ (((x >> 15) & 0x00010001u) * 0x7FFFu);
            int h0 = (int)((kk >> 8) & 0xFFu);
            int h1 = (int)(kk >> 24);
            float r0 = fmaxf(bf2f(x & 0xFFFFu) - 0.2f, 0.0f);
            float r1 = fmaxf(bf2f(x >> 16) - 0.2f, 0.0f);
            sloc += (h0 > bb) ? r0 : 0.0f;
            sloc += (h1 > bb) ? r1 : 0.0f;
            if (h0 == bb) {
                unsigned lb_ = kk & 0xFFu;
                atomicAdd(&lowcnt[lb_], 1u); atomicAdd(&lowsum[lb_], r0);
            }
            if (h1 == bb) {
                unsigned lb_ = (kk >> 16) & 0xFFu;
                atomicAdd(&lowcnt[lb_], 1u); atomicAdd(&lowsum[lb_], r1);
            }
        }
    }
    #pragma unroll
    for (int off = 32; off >= 1; off >>= 1) sloc += __shfl_down(sloc, off);
    if (lane == 0) s_s[wave] = sloc;
    __syncthreads();

    if (wave != 0) return;

    // ---- wave 0: joint suffix scan (count + float sum) over 256 low bins.
    // Boundary lane finishes the row: no extra barrier, no tail loop.
    {
        int c0 = (int)lowcnt[4*lane+0], c1 = (int)lowcnt[4*lane+1];
        int c2 = (int)lowcnt[4*lane+2], c3 = (int)lowcnt[4*lane+3];
        float f0 = lowsum[4*lane+0], f1 = lowsum[4*lane+1];
        float f2 = lowsum[4*lane+2], f3 = lowsum[4*lane+3];
        int suf3 = c3, suf2 = c2 + suf3, suf1 = c1 + suf2, suf0 = c0 + suf1;
        float fs3 = f3, fs2 = f2 + fs3, fs1 = f1 + fs2, fs0 = f0 + fs1;
        int inc = suf0; float finc = fs0;
        #pragma unroll
        for (int off = 1; off < 64; off <<= 1) {
            int   ti = __shfl_down(inc, off);
            float tf = __shfl_down(finc, off);
            bool ok = (lane + off < 64);
            inc  += ok ? ti : 0;
            finc += ok ? tf : 0.0f;
        }
        int   eAbove = inc - suf0;
        float fAbove = finc - fs0;
        int S0 = suf0 + eAbove, S1 = suf1 + eAbove, S2 = suf2 + eAbove, S3 = suf3 + eAbove;
        int SN0 = S1, SN1 = S2, SN2 = S3, SN3 = eAbove;
        float F0 = fs1 + fAbove, F1 = fs2 + fAbove, F2 = fs3 + fAbove, F3 = fAbove;

        int lb = -1, r2 = 0; float above = 0.f;
        if (S0 >= r && SN0 < r) { lb = 4*lane+0; r2 = r - SN0; above = F0; }
        if (S1 >= r && SN1 < r) { lb = 4*lane+1; r2 = r - SN1; above = F1; }
        if (S2 >= r && SN2 < r) { lb = 4*lane+2; r2 = r - SN2; above = F2; }
        if (S3 >= r && SN3 < r) { lb = 4*lane+3; r2 = r - SN3; above = F3; }
        if (lb >= 0) {   // exactly one lane
            unsigned kt = ((unsigned)bb << 8) | (unsigned)lb;
            unsigned bt = kt ^ ((kt & 0x8000u) ? 0x8000u : 0xFFFFu);
            float vt = bf2f(bt);   // exact value of every element in this cell
            float total = s_s[0] + s_s[1] + s_s[2] + s_s[3] + above
                        + (float)r2 * fmaxf(vt - 0.2f, 0.0f);
            atomicAdd(out, total * INV_DENOM);
        }
    }
}

extern "C" void kernel_launch(void* const* d_in, const int* in_sizes, int n_in,
                              void* d_out, int out_size, void* d_ws, size_t ws_size,
                              hipStream_t stream) {
    const float* wkp1  = (const float*)d_in[1];
    const float* kp2   = (const float*)d_in[2];
    const float* kp1d  = (const float*)d_in[3];
    const float* kp2d  = (const float*)d_in[4];
    const float* desc2 = (const float*)d_in[5];
    float* out = (float*)d_out;

    ushort* Abf = (ushort*)d_ws;                 // 2 MB
    ushort* Bbf = Abf + (size_t)N1 * CDIM;       // 2 MB
    ushort* dots = Bbf + (size_t)N2 * CDIM;      // remainder: desc_dot chunks (bf16)

    size_t desc_bytes = (size_t)(N1 + N2) * CDIM * sizeof(ushort);
    size_t avail = (ws_size > desc_bytes) ? (ws_size - desc_bytes) : 0;
    long rows_chunk = (long)(avail / ((size_t)N2 * sizeof(ushort)));
    rows_chunk = (rows_chunk / 128) * 128;
    if (rows_chunk > N1) rows_chunk = N1;
    if (rows_chunk < 128) rows_chunk = 128;      // requires ws >= ~6 MB

    hipMemsetAsync(d_out, 0, sizeof(float), stream);

    int n4 = N1 * CDIM / 4;
    cvt_kernel<<<(n4 + 255) / 256, 256, 0, stream>>>(kp1d, Abf, n4);
    cvt_kernel<<<(n4 + 255) / 256, 256, 0, stream>>>(kp2d, Bbf, n4);

    pos_kernel<<<N1, 128, 0, stream>>>(wkp1, kp1d, desc2, out);

    for (int r0 = 0; r0 < N1; r0 += (int)rows_chunk) {
        int rows = (int)((N1 - r0 < rows_chunk) ? (N1 - r0) : rows_chunk);
        dim3 grid(N2 / 128, rows / 128);
        gemm_kernel<<<grid, 256, 0, stream>>>(Abf, Bbf, wkp1, kp2, dots, r0);
        select_kernel<<<rows, 256, 0, stream>>>(dots, out);
    }
}

// Round 7
// 417.751 us; speedup vs baseline: 1.0925x; 1.0925x over previous
//
#include <hip/hip_runtime.h>
#include <hip/hip_bf16.h>

#define N1 8192
#define N2 8192
#define CDIM 128
#define HC 60
#define WC 80
#define HIMG 480
#define WIMG 640
#define INV_DENOM (1.0f / (8192.0f * 256.0f))

using bf16x8 = __attribute__((ext_vector_type(8))) short;
using f32x4  = __attribute__((ext_vector_type(4))) float;

__device__ __forceinline__ ushort f2bf(float f) {
    union { float f; unsigned u; } x; x.f = f;
    unsigned u = x.u;
    unsigned r = (u + 0x7FFFu + ((u >> 16) & 1u)) >> 16;
    return (ushort)r;
}
__device__ __forceinline__ float bf2f(unsigned bits) {
    union { unsigned u; float f; } x; x.u = bits << 16; return x.f;
}

// ---------- fp32 -> bf16 convert (vectorized) ----------
__global__ void cvt_kernel(const float* __restrict__ in, ushort* __restrict__ out, int n4) {
    int i = blockIdx.x * blockDim.x + threadIdx.x;
    if (i < n4) {
        float4 v = ((const float4*)in)[i];
        ushort4 o;
        o.x = f2bf(v.x); o.y = f2bf(v.y); o.z = f2bf(v.z); o.w = f2bf(v.w);
        ((ushort4*)out)[i] = o;
    }
}

// ---------- positive term ----------
__global__ void pos_kernel(const float* __restrict__ wkp1,
                           const float* __restrict__ kp1d,
                           const float* __restrict__ desc2,
                           float* __restrict__ out) {
    const int i = blockIdx.x;
    const int c = threadIdx.x;            // 128 threads = 2 waves
    float y = wkp1[2 * i], x = wkp1[2 * i + 1];
    float py = fminf(fmaxf(y / (float)(HIMG - 1) * (float)(HC - 1), 0.0f), (float)(HC - 1));
    float px = fminf(fmaxf(x / (float)(WIMG - 1) * (float)(WC - 1), 0.0f), (float)(WC - 1));
    int y0 = min(max((int)floorf(py), 0), HC - 2);
    int x0 = min(max((int)floorf(px), 0), WC - 2);
    float wy = py - (float)y0;
    float wx = px - (float)x0;
    const float* d = desc2 + (size_t)c * (HC * WC) + y0 * WC + x0;
    float v00 = d[0], v01 = d[1], v10 = d[WC], v11 = d[WC + 1];
    float v = v00 * (1.0f - wy) * (1.0f - wx) + v01 * (1.0f - wy) * wx
            + v10 * wy * (1.0f - wx) + v11 * wy * wx;
    float a = kp1d[(size_t)i * CDIM + c];
    float s2 = v * v, sav = a * v;
    #pragma unroll
    for (int off = 32; off >= 1; off >>= 1) {
        s2  += __shfl_down(s2, off);
        sav += __shfl_down(sav, off);
    }
    __shared__ float p2[2], pav[2];
    int wave = threadIdx.x >> 6, lane = threadIdx.x & 63;
    if (lane == 0) { p2[wave] = s2; pav[wave] = sav; }
    __syncthreads();
    if (threadIdx.x == 0) {
        float nrm = sqrtf(p2[0] + p2[1]);
        float pd = (pav[0] + pav[1]) / fmaxf(nrm, 1e-12f);
        float l = fmaxf(1.0f - pd, 0.0f) * (256.0f / 3.0f);
        atomicAdd(out, l * INV_DENOM);
    }
}

// ---------- masked GEMM -> bf16 dots ----------
__global__ __launch_bounds__(256, 2)
void gemm_kernel(const ushort* __restrict__ A, const ushort* __restrict__ B,
                 const float* __restrict__ wkp1, const float* __restrict__ kp2,
                 ushort* __restrict__ dots, int m_off) {
    const int n0 = blockIdx.x * 128;
    const int m0 = m_off + blockIdx.y * 128;
    const int lane = threadIdx.x & 63;
    const int wave = threadIdx.x >> 6;
    const int wm = wave >> 1, wn = wave & 1;
    const int lrow = lane & 15, quad = lane >> 4;

    f32x4 acc[4][4];
    #pragma unroll
    for (int i = 0; i < 4; i++)
        #pragma unroll
        for (int j = 0; j < 4; j++) acc[i][j] = (f32x4){0.f, 0.f, 0.f, 0.f};

    const int mbase = m0 + wm * 64 + lrow;
    const int nbase = n0 + wn * 64 + lrow;
    #pragma unroll
    for (int kit = 0; kit < 4; kit++) {
        const int kk = kit * 32 + quad * 8;
        bf16x8 af[4], bfr[4];
        #pragma unroll
        for (int t = 0; t < 4; t++) {
            af[t]  = *(const bf16x8*)(A + (size_t)(mbase + t * 16) * CDIM + kk);
            bfr[t] = *(const bf16x8*)(B + (size_t)(nbase + t * 16) * CDIM + kk);
        }
        #pragma unroll
        for (int mt = 0; mt < 4; mt++)
            #pragma unroll
            for (int nt = 0; nt < 4; nt++)
                acc[mt][nt] = __builtin_amdgcn_mfma_f32_16x16x32_bf16(
                    af[mt], bfr[nt], acc[mt][nt], 0, 0, 0);
    }

    const float thr = 2.0f * sqrtf(32.0f) + 0.1f;
    const float thr2 = thr * thr;
    #pragma unroll
    for (int nt = 0; nt < 4; nt++) {
        int j = n0 + wn * 64 + nt * 16 + lrow;       // C/D: col = lane&15
        float ky = kp2[2 * j], kx = kp2[2 * j + 1];
        #pragma unroll
        for (int mt = 0; mt < 4; mt++) {
            #pragma unroll
            for (int r = 0; r < 4; r++) {
                int i = m0 + wm * 64 + mt * 16 + quad * 4 + r;  // row = (lane>>4)*4 + reg
                float wy = wkp1[2 * i], wx = wkp1[2 * i + 1];
                float dy = wy - ky, dx = wx - kx;
                float v = acc[mt][nt][r];
                if (dy * dy + dx * dx <= thr2) v -= 5.0f;
                dots[(size_t)(i - m_off) * N2 + j] = f2bf(v);
            }
        }
    }
}

// ---------- per-row top-256 hinge sum (LDS-staged ballot bisection) ----------
// Row -> monotone u16 keys -> LDS once (16 KB). 16 integer bisection iters;
// counts via __ballot + popcount (SALU) -- ZERO per-element LDS atomics
// (R5/R6's serialization), zero register-residency requirements (R2-R4's
// remat trap: the compiler cannot remat a ds_read from global, and the
// in-loop __syncthreads legally forces the per-iter LDS re-read we budget).
// Stride-1 ds_read_b128 = the measured-good conflict-free pattern.
__global__ __launch_bounds__(256)
void select_kernel(const ushort* __restrict__ dots, float* __restrict__ out) {
    const int row = blockIdx.x;
    const int t = threadIdx.x;
    const int lane = t & 63, wave = t >> 6;

    __shared__ uint4 skey[1024];          // 8192 u16 keys, 16 KB
    __shared__ int s_cnt[2][4];
    __shared__ float s_s[4];
    __shared__ int s_c[4];

    const uint4* rp4 = (const uint4*)(dots + (size_t)row * N2);  // 8 bf16 per uint4
    #pragma unroll
    for (int q = 0; q < 4; q++) {
        uint4 w = rp4[q * 256 + t];
        uint4 kq;   // packed pair of monotone u16 keys per u32
        kq.x = w.x ^ 0x80008000u ^ (((w.x >> 15) & 0x00010001u) * 0x7FFFu);
        kq.y = w.y ^ 0x80008000u ^ (((w.y >> 15) & 0x00010001u) * 0x7FFFu);
        kq.z = w.z ^ 0x80008000u ^ (((w.z >> 15) & 0x00010001u) * 0x7FFFu);
        kq.w = w.w ^ 0x80008000u ^ (((w.w >> 15) & 0x00010001u) * 0x7FFFu);
        skey[q * 256 + t] = kq;
    }
    __syncthreads();

    int lo = -1, hi = 65535;   // invariant: cnt(>lo) >= 256, cnt(>hi) <= 255
    #pragma unroll 1
    for (int it = 0; it < 16; it++) {
        unsigned mid = (unsigned)((lo + hi) >> 1);
        int c = 0;
        #pragma unroll
        for (int q = 0; q < 4; q++) {
            uint4 kq = skey[q * 256 + t];
            c += (int)__popcll(__ballot((kq.x & 0xFFFFu) > mid));
            c += (int)__popcll(__ballot((kq.x >> 16)     > mid));
            c += (int)__popcll(__ballot((kq.y & 0xFFFFu) > mid));
            c += (int)__popcll(__ballot((kq.y >> 16)     > mid));
            c += (int)__popcll(__ballot((kq.z & 0xFFFFu) > mid));
            c += (int)__popcll(__ballot((kq.z >> 16)     > mid));
            c += (int)__popcll(__ballot((kq.w & 0xFFFFu) > mid));
            c += (int)__popcll(__ballot((kq.w >> 16)     > mid));
        }
        if (lane == 0) s_cnt[it & 1][wave] = c;
        __syncthreads();   // slot alternation makes 1 barrier/iter safe
        int total = s_cnt[it & 1][0] + s_cnt[it & 1][1]
                  + s_cnt[it & 1][2] + s_cnt[it & 1][3];
        if (total >= 256) lo = (int)mid; else hi = (int)mid;
    }
    const unsigned kt = (unsigned)hi;     // key of 256th-largest (attained)

    // epilogue: exact closed form under ties
    float s = 0.f; int cgt = 0;
    #pragma unroll
    for (int q = 0; q < 4; q++) {
        uint4 kq = skey[q * 256 + t];
        unsigned halves[8] = {kq.x & 0xFFFFu, kq.x >> 16, kq.y & 0xFFFFu, kq.y >> 16,
                              kq.z & 0xFFFFu, kq.z >> 16, kq.w & 0xFFFFu, kq.w >> 16};
        #pragma unroll
        for (int u = 0; u < 8; u++) {
            unsigned k = halves[u];
            bool gt = k > kt;
            cgt += (int)__popcll(__ballot(gt));     // wave-uniform count
            if (gt) {
                unsigned b = k ^ ((k & 0x8000u) ? 0x8000u : 0xFFFFu);
                s += fmaxf(bf2f(b) - 0.2f, 0.0f);
            }
        }
    }
    #pragma unroll
    for (int off = 32; off >= 1; off >>= 1) s += __shfl_down(s, off);
    if (lane == 0) { s_s[wave] = s; s_c[wave] = cgt; }
    __syncthreads();
    if (t == 0) {
        unsigned bt = kt ^ ((kt & 0x8000u) ? 0x8000u : 0xFFFFu);
        float vt = bf2f(bt);
        float st = s_s[0] + s_s[1] + s_s[2] + s_s[3];
        int ct = s_c[0] + s_c[1] + s_c[2] + s_c[3];
        float S = st + (float)(256 - ct) * fmaxf(vt - 0.2f, 0.0f);
        atomicAdd(out, S * INV_DENOM);
    }
}

extern "C" void kernel_launch(void* const* d_in, const int* in_sizes, int n_in,
                              void* d_out, int out_size, void* d_ws, size_t ws_size,
                              hipStream_t stream) {
    const float* wkp1  = (const float*)d_in[1];
    const float* kp2   = (const float*)d_in[2];
    const float* kp1d  = (const float*)d_in[3];
    const float* kp2d  = (const float*)d_in[4];
    const float* desc2 = (const float*)d_in[5];
    float* out = (float*)d_out;

    ushort* Abf = (ushort*)d_ws;                 // 2 MB
    ushort* Bbf = Abf + (size_t)N1 * CDIM;       // 2 MB
    ushort* dots = Bbf + (size_t)N2 * CDIM;      // remainder: desc_dot chunks (bf16)

    size_t desc_bytes = (size_t)(N1 + N2) * CDIM * sizeof(ushort);
    size_t avail = (ws_size > desc_bytes) ? (ws_size - desc_bytes) : 0;
    long rows_chunk = (long)(avail / ((size_t)N2 * sizeof(ushort)));
    rows_chunk = (rows_chunk / 128) * 128;
    if (rows_chunk > N1) rows_chunk = N1;
    if (rows_chunk < 128) rows_chunk = 128;      // requires ws >= ~6 MB

    hipMemsetAsync(d_out, 0, sizeof(float), stream);

    int n4 = N1 * CDIM / 4;
    cvt_kernel<<<(n4 + 255) / 256, 256, 0, stream>>>(kp1d, Abf, n4);
    cvt_kernel<<<(n4 + 255) / 256, 256, 0, stream>>>(kp2d, Bbf, n4);

    pos_kernel<<<N1, 128, 0, stream>>>(wkp1, kp1d, desc2, out);

    for (int r0 = 0; r0 < N1; r0 += (int)rows_chunk) {
        int rows = (int)((N1 - r0 < rows_chunk) ? (N1 - r0) : rows_chunk);
        dim3 grid(N2 / 128, rows / 128);
        gemm_kernel<<<grid, 256, 0, stream>>>(Abf, Bbf, wkp1, kp2, dots, r0);
        select_kernel<<<rows, 256, 0, stream>>>(dots, out);
    }
}